// Round 4
// baseline (110.632 us; speedup 1.0000x reference)
//
#include <hip/hip_runtime.h>

#define F 16
#define XL 128

// bands layout in d_ws: float bands[2][5][128]
//   pass 0 = row operator (x/w direction), pass 1 = column operator (y/h)
//   bands[p][d][pos] = coefficient of u[pos + d - 2] in deviation at pos.
//   Out-of-range taps stored as 0.

__device__ __forceinline__ float g1f(const float* __restrict__ w1,
                                     const float* __restrict__ w1L,
                                     const float* __restrict__ w1R,
                                     int f, int v, int wp) {
  // coefficient of u[wp] in first-order field dX[f, v]
  if (v == 0) {
    if (wp == 0) return w1L[f * 2 + 0];
    if (wp == 1) return w1L[f * 2 + 1];
    return 0.f;
  }
  if (v == XL - 1) {
    if (wp == XL - 2) return w1R[f * 2 + 0];
    if (wp == XL - 1) return w1R[f * 2 + 1];
    return 0.f;
  }
  int k = wp - (v - 1);
  return (k >= 0 && k < 3) ? w1[f * 3 + k] : 0.f;
}

__global__ __launch_bounds__(256)
void build_bands_kernel(const float* __restrict__ wX1, const float* __restrict__ wX1L,
                        const float* __restrict__ wX1R, const float* __restrict__ wY1,
                        const float* __restrict__ wY1L, const float* __restrict__ wY1R,
                        const float* __restrict__ wX2, const float* __restrict__ wX2L,
                        const float* __restrict__ wX2R, const float* __restrict__ wY2,
                        const float* __restrict__ wY2L, const float* __restrict__ wY2R,
                        const float* __restrict__ wfc, float* __restrict__ bands) {
  __shared__ float r1s[2][3], r1Ls[2][2], r1Rs[2][2];
  __shared__ float qs[2][F][3], qLs[2][F][2], qRs[2][F][2];

  const int t = threadIdx.x;
  if (t < 6) {
    int p = t / 3, k = t % 3;
    const float* w1 = p ? wY1 : wX1;
    int off = p ? F : 0;
    float s = 0.f;
    for (int f = 0; f < F; ++f) s += wfc[off + f] * w1[f * 3 + k];
    r1s[p][k] = s;
  } else if (t < 10) {
    int t2 = t - 6; int p = t2 / 2, k = t2 % 2;
    const float* w1L = p ? wY1L : wX1L;
    int off = p ? F : 0;
    float s = 0.f;
    for (int f = 0; f < F; ++f) s += wfc[off + f] * w1L[f * 2 + k];
    r1Ls[p][k] = s;
  } else if (t < 14) {
    int t2 = t - 10; int p = t2 / 2, k = t2 % 2;
    const float* w1R = p ? wY1R : wX1R;
    int off = p ? F : 0;
    float s = 0.f;
    for (int f = 0; f < F; ++f) s += wfc[off + f] * w1R[f * 2 + k];
    r1Rs[p][k] = s;
  } else if (t < 14 + 96) {
    int t2 = t - 14; int p = t2 / 48; int r = t2 % 48; int fi = r / 3, k = r % 3;
    const float* w2 = p ? wY2 : wX2;
    int off = p ? 3 * F : 2 * F;
    float s = 0.f;
    for (int fo = 0; fo < F; ++fo) s += wfc[off + fo] * w2[(fo * F + fi) * 3 + k];
    qs[p][fi][k] = s;
  } else if (t < 110 + 64) {
    int t2 = t - 110; int p = t2 / 32; int r = t2 % 32; int fi = r / 2, k = r % 2;
    const float* w2L = p ? wY2L : wX2L;
    int off = p ? 3 * F : 2 * F;
    float s = 0.f;
    for (int fo = 0; fo < F; ++fo) s += wfc[off + fo] * w2L[(fo * F + fi) * 2 + k];
    qLs[p][fi][k] = s;
  } else if (t < 174 + 64) {
    int t2 = t - 174; int p = t2 / 32; int r = t2 % 32; int fi = r / 2, k = r % 2;
    const float* w2R = p ? wY2R : wX2R;
    int off = p ? 3 * F : 2 * F;
    float s = 0.f;
    for (int fo = 0; fo < F; ++fo) s += wfc[off + fo] * w2R[(fo * F + fi) * 2 + k];
    qRs[p][fi][k] = s;
  }
  __syncthreads();

  int gid = blockIdx.x * 256 + t;
  if (gid >= 2 * XL * 5) return;
  const int p = gid / (XL * 5);
  const int rem = gid % (XL * 5);
  const int w = rem / 5;
  const int d = rem % 5;
  const int wp = w + d - 2;

  const float* w1  = p ? wY1  : wX1;
  const float* w1L = p ? wY1L : wX1L;
  const float* w1R = p ? wY1R : wX1R;

  float c = 0.f;
  if (wp >= 0 && wp < XL) {
    if (w == 0) {
      if (wp == 0)       c += r1Ls[p][0];
      else if (wp == 1)  c += r1Ls[p][1];
    } else if (w == XL - 1) {
      if (wp == XL - 2)      c += r1Rs[p][0];
      else if (wp == XL - 1) c += r1Rs[p][1];
    } else {
      int k = wp - (w - 1);
      if (k >= 0 && k < 3) c += r1s[p][k];
    }
    if (w == 0) {
      for (int vi = 0; vi < 2; ++vi)
        for (int fi = 0; fi < F; ++fi)
          c += qLs[p][fi][vi] * g1f(w1, w1L, w1R, fi, vi, wp);
    } else if (w == XL - 1) {
      for (int vi = 0; vi < 2; ++vi)
        for (int fi = 0; fi < F; ++fi)
          c += qRs[p][fi][vi] * g1f(w1, w1L, w1R, fi, XL - 2 + vi, wp);
    } else {
      for (int k2 = 0; k2 < 3; ++k2) {
        int v = w - 1 + k2;
        for (int fi = 0; fi < F; ++fi)
          c += qs[p][fi][k2] * g1f(w1, w1L, w1R, fi, v, wp);
      }
    }
  }
  bands[(p * 5 + d) * XL + w] = c;
}

// 512 blocks = 64 images x 8 strips (16 interior rows + 16-row halos each
// side where present => 48-row buffer). 512 threads = 8 waves; LDS padded to
// ~56 KB so exactly 2 blocks co-reside per CU (two INDEPENDENT barrier
// domains, 4 waves/SIMD). Each thread owns 4 cols x 3 rows. Final iteration
// streams straight to global (only 16 valid interior rows stored).
#define BR 48   // buffer rows
__global__ __launch_bounds__(512, 4)
void fd_main_kernel(const float* __restrict__ x_in, const float* __restrict__ bands,
                    const int* __restrict__ fdp, float* __restrict__ x_out) {
  __shared__ __align__(16) float buf[2][BR * XL + 512];  // +512 pad: forces <=2 blocks/CU
  __shared__ float cbl[5 * XL];                          // col band table (boundary rows)

  const int tid = threadIdx.x;
  const int n = blockIdx.x >> 3;
  const int s = blockIdx.x & 7;
  int g0 = 16 * s - 16; if (g0 < 0) g0 = 0; if (g0 > XL - BR) g0 = XL - BR;
  const int l0 = 16 * s - g0;      // local row of first interior row

  // stage strip rows [g0, g0+48) into buf[0]: 1536 float4 / 512 threads
  {
    const float4* sg4 = (const float4*)(x_in + n * (XL * XL) + g0 * XL);
    float4* b4 = (float4*)buf[0];
    b4[tid] = sg4[tid];
    b4[tid + 512] = sg4[tid + 512];
    b4[tid + 1024] = sg4[tid + 1024];
  }
  if (tid < XL) {
#pragma unroll
    for (int d = 0; d < 5; ++d) cbl[d * XL + tid] = bands[(5 + d) * XL + tid];
  }

  const int q = tid & 31;             // column quad: cols 4q..4q+3
  const int rbase = (tid >> 5) * 3;   // rows [rbase, rbase+3), rbase in 0..45
  const int plm = (q > 0) ? 2 * q - 1 : 0;    // left halo pair (cols 4q-2,4q-1)
  const int prm = (q < 31) ? 2 * q + 2 : 63;  // right halo pair (cols 4q+4,4q+5)

  // row-band coefficients for this thread's 4 columns (OOB taps are 0)
  const float4 rb0 = ((const float4*)(bands + 0 * XL))[q];
  const float4 rb1 = ((const float4*)(bands + 1 * XL))[q];
  const float4 rb2 = ((const float4*)(bands + 2 * XL))[q];
  const float4 rb3 = ((const float4*)(bands + 3 * XL))[q];
  const float4 rb4 = ((const float4*)(bands + 4 * XL))[q];
  // interior column-band coefficients (position-independent for rows 2..125)
  const float cbi0 = bands[(5 + 0) * XL + 64];
  const float cbi1 = bands[(5 + 1) * XL + 64];
  const float cbi2 = bands[(5 + 2) * XL + 64];
  const float cbi3 = bands[(5 + 3) * XL + 64];
  const float cbi4 = bands[(5 + 4) * XL + 64];

  const int fdb = fdp[0];
  float4* out4 = (float4*)(x_out + n * (XL * XL));

  __syncthreads();

  if (fdb == 0) {   // copy-through
    const float4* bc = (const float4*)buf[0];
#pragma unroll
    for (int j = 0; j < 3; ++j) {
      const int r = rbase + j;
      const int lr = r - l0;
      if (lr >= 0 && lr < 16) out4[(16 * s + lr) * 32 + q] = bc[r * 32 + q];
    }
    return;
  }

  // one time-step over this thread's 3 rows; stores via callback
  auto step = [&](const float* bufc, auto&& emit) {
    const float4* bc  = (const float4*)bufc;
    const float2* bc2 = (const float2*)bufc;
    float4 c_m2 = bc[((rbase >= 2) ? rbase - 2 : 0) * 32 + q];
    float4 c_m1 = bc[((rbase >= 1) ? rbase - 1 : 0) * 32 + q];
    float4 c_0  = bc[(rbase + 0) * 32 + q];
    float4 c_p1 = bc[(rbase + 1) * 32 + q];
    float4 c_p2 = bc[(rbase + 2) * 32 + q];
#pragma unroll
    for (int j = 0; j < 3; ++j) {
      const int r = rbase + j;
      const int gh = g0 + r;
      const float2 hl = bc2[r * 64 + plm];
      const float2 hr = bc2[r * 64 + prm];
      float b0 = cbi0, b1 = cbi1, b2 = cbi2, b3 = cbi3, b4c = cbi4;
      if (gh < 2 || gh > 125) {
        b0 = cbl[0 * XL + gh]; b1 = cbl[1 * XL + gh]; b2 = cbl[2 * XL + gh];
        b3 = cbl[3 * XL + gh]; b4c = cbl[4 * XL + gh];
      }
      float4 a;
      a.x = c_0.x
        + rb0.x * hl.x  + rb1.x * hl.y  + rb2.x * c_0.x + rb3.x * c_0.y + rb4.x * c_0.z
        + b0 * c_m2.x + b1 * c_m1.x + b2 * c_0.x + b3 * c_p1.x + b4c * c_p2.x;
      a.y = c_0.y
        + rb0.y * hl.y  + rb1.y * c_0.x + rb2.y * c_0.y + rb3.y * c_0.z + rb4.y * c_0.w
        + b0 * c_m2.y + b1 * c_m1.y + b2 * c_0.y + b3 * c_p1.y + b4c * c_p2.y;
      a.z = c_0.z
        + rb0.z * c_0.x + rb1.z * c_0.y + rb2.z * c_0.z + rb3.z * c_0.w + rb4.z * hr.x
        + b0 * c_m2.z + b1 * c_m1.z + b2 * c_0.z + b3 * c_p1.z + b4c * c_p2.z;
      a.w = c_0.w
        + rb0.w * c_0.y + rb1.w * c_0.z + rb2.w * c_0.w + rb3.w * hr.x  + rb4.w * hr.y
        + b0 * c_m2.w + b1 * c_m1.w + b2 * c_0.w + b3 * c_p1.w + b4c * c_p2.w;
      emit(r, a);
      if (j < 2) {   // roll window down one row (skip wasted final roll)
        c_m2 = c_m1; c_m1 = c_0; c_0 = c_p1; c_p1 = c_p2;
        const int rn = (r + 3 <= BR - 1) ? r + 3 : BR - 1;
        c_p2 = bc[rn * 32 + q];
      }
    }
  };

  for (int t = 0; t < fdb - 1; ++t) {
    float4* bn = (float4*)buf[(t & 1) ^ 1];
    step(buf[t & 1], [&](int r, float4 a) { bn[r * 32 + q] = a; });
    __syncthreads();
  }
  // final iteration: straight to global
  step(buf[(fdb - 1) & 1], [&](int r, float4 a) {
    const int lr = r - l0;
    if (lr >= 0 && lr < 16) out4[(16 * s + lr) * 32 + q] = a;
  });
}

extern "C" void kernel_launch(void* const* d_in, const int* in_sizes, int n_in,
                              void* d_out, int out_size, void* d_ws, size_t ws_size,
                              hipStream_t stream) {
  const float* xInput = (const float*)d_in[0];
  const float* wX1  = (const float*)d_in[1];
  const float* wX1L = (const float*)d_in[2];
  const float* wX1R = (const float*)d_in[3];
  const float* wY1  = (const float*)d_in[4];
  const float* wY1L = (const float*)d_in[5];
  const float* wY1R = (const float*)d_in[6];
  const float* wX2  = (const float*)d_in[7];
  const float* wX2L = (const float*)d_in[8];
  const float* wX2R = (const float*)d_in[9];
  const float* wY2  = (const float*)d_in[10];
  const float* wY2L = (const float*)d_in[11];
  const float* wY2R = (const float*)d_in[12];
  const float* wfc  = (const float*)d_in[13];
  const int*   fdp  = (const int*)d_in[14];

  float* bands = (float*)d_ws;   // 2*5*128 floats = 5120 B
  float* out = (float*)d_out;

  build_bands_kernel<<<5, 256, 0, stream>>>(wX1, wX1L, wX1R, wY1, wY1L, wY1R,
                                            wX2, wX2L, wX2R, wY2, wY2L, wY2R,
                                            wfc, bands);
  fd_main_kernel<<<512, 512, 0, stream>>>(xInput, bands, fdp, out);
}

// Round 5
// 103.394 us; speedup vs baseline: 1.0700x; 1.0700x over previous
//
#include <hip/hip_runtime.h>

#define F 16
#define XL 128

// bands layout in d_ws: float bands[2][5][128]
//   pass 0 = row operator (x/w direction), pass 1 = column operator (y/h)
//   bands[p][d][pos] = coefficient of u[pos + d - 2] in deviation at pos.
//   Out-of-range taps stored as 0 (so garbage neighbors are annihilated).

__device__ __forceinline__ float g1f(const float* __restrict__ w1,
                                     const float* __restrict__ w1L,
                                     const float* __restrict__ w1R,
                                     int f, int v, int wp) {
  if (v == 0) {
    if (wp == 0) return w1L[f * 2 + 0];
    if (wp == 1) return w1L[f * 2 + 1];
    return 0.f;
  }
  if (v == XL - 1) {
    if (wp == XL - 2) return w1R[f * 2 + 0];
    if (wp == XL - 1) return w1R[f * 2 + 1];
    return 0.f;
  }
  int k = wp - (v - 1);
  return (k >= 0 && k < 3) ? w1[f * 3 + k] : 0.f;
}

__global__ __launch_bounds__(256)
void build_bands_kernel(const float* __restrict__ wX1, const float* __restrict__ wX1L,
                        const float* __restrict__ wX1R, const float* __restrict__ wY1,
                        const float* __restrict__ wY1L, const float* __restrict__ wY1R,
                        const float* __restrict__ wX2, const float* __restrict__ wX2L,
                        const float* __restrict__ wX2R, const float* __restrict__ wY2,
                        const float* __restrict__ wY2L, const float* __restrict__ wY2R,
                        const float* __restrict__ wfc, float* __restrict__ bands) {
  __shared__ float r1s[2][3], r1Ls[2][2], r1Rs[2][2];
  __shared__ float qs[2][F][3], qLs[2][F][2], qRs[2][F][2];

  const int t = threadIdx.x;
  if (t < 6) {
    int p = t / 3, k = t % 3;
    const float* w1 = p ? wY1 : wX1;
    int off = p ? F : 0;
    float s = 0.f;
    for (int f = 0; f < F; ++f) s += wfc[off + f] * w1[f * 3 + k];
    r1s[p][k] = s;
  } else if (t < 10) {
    int t2 = t - 6; int p = t2 / 2, k = t2 % 2;
    const float* w1L = p ? wY1L : wX1L;
    int off = p ? F : 0;
    float s = 0.f;
    for (int f = 0; f < F; ++f) s += wfc[off + f] * w1L[f * 2 + k];
    r1Ls[p][k] = s;
  } else if (t < 14) {
    int t2 = t - 10; int p = t2 / 2, k = t2 % 2;
    const float* w1R = p ? wY1R : wX1R;
    int off = p ? F : 0;
    float s = 0.f;
    for (int f = 0; f < F; ++f) s += wfc[off + f] * w1R[f * 2 + k];
    r1Rs[p][k] = s;
  } else if (t < 14 + 96) {
    int t2 = t - 14; int p = t2 / 48; int r = t2 % 48; int fi = r / 3, k = r % 3;
    const float* w2 = p ? wY2 : wX2;
    int off = p ? 3 * F : 2 * F;
    float s = 0.f;
    for (int fo = 0; fo < F; ++fo) s += wfc[off + fo] * w2[(fo * F + fi) * 3 + k];
    qs[p][fi][k] = s;
  } else if (t < 110 + 64) {
    int t2 = t - 110; int p = t2 / 32; int r = t2 % 32; int fi = r / 2, k = r % 2;
    const float* w2L = p ? wY2L : wX2L;
    int off = p ? 3 * F : 2 * F;
    float s = 0.f;
    for (int fo = 0; fo < F; ++fo) s += wfc[off + fo] * w2L[(fo * F + fi) * 2 + k];
    qLs[p][fi][k] = s;
  } else if (t < 174 + 64) {
    int t2 = t - 174; int p = t2 / 32; int r = t2 % 32; int fi = r / 2, k = r % 2;
    const float* w2R = p ? wY2R : wX2R;
    int off = p ? 3 * F : 2 * F;
    float s = 0.f;
    for (int fo = 0; fo < F; ++fo) s += wfc[off + fo] * w2R[(fo * F + fi) * 2 + k];
    qRs[p][fi][k] = s;
  }
  __syncthreads();

  int gid = blockIdx.x * 256 + t;
  if (gid >= 2 * XL * 5) return;
  const int p = gid / (XL * 5);
  const int rem = gid % (XL * 5);
  const int w = rem / 5;
  const int d = rem % 5;
  const int wp = w + d - 2;

  const float* w1  = p ? wY1  : wX1;
  const float* w1L = p ? wY1L : wX1L;
  const float* w1R = p ? wY1R : wX1R;

  float c = 0.f;
  if (wp >= 0 && wp < XL) {
    if (w == 0) {
      if (wp == 0)       c += r1Ls[p][0];
      else if (wp == 1)  c += r1Ls[p][1];
    } else if (w == XL - 1) {
      if (wp == XL - 2)      c += r1Rs[p][0];
      else if (wp == XL - 1) c += r1Rs[p][1];
    } else {
      int k = wp - (w - 1);
      if (k >= 0 && k < 3) c += r1s[p][k];
    }
    if (w == 0) {
      for (int vi = 0; vi < 2; ++vi)
        for (int fi = 0; fi < F; ++fi)
          c += qLs[p][fi][vi] * g1f(w1, w1L, w1R, fi, vi, wp);
    } else if (w == XL - 1) {
      for (int vi = 0; vi < 2; ++vi)
        for (int fi = 0; fi < F; ++fi)
          c += qRs[p][fi][vi] * g1f(w1, w1L, w1R, fi, XL - 2 + vi, wp);
    } else {
      for (int k2 = 0; k2 < 3; ++k2) {
        int v = w - 1 + k2;
        for (int fi = 0; fi < F; ++fi)
          c += qs[p][fi][k2] * g1f(w1, w1L, w1R, fi, v, wp);
      }
    }
  }
  bands[(p * 5 + d) * XL + w] = c;
}

// DPP whole-wave lane shifts (VALU pipe, no LDS). shr1: lane i <- lane i-1
// (lane 0 gets 0); shl1: lane i <- lane i+1 (lane 63 gets 0).
__device__ __forceinline__ float dpp_shr1(float x) {
  return __int_as_float(
      __builtin_amdgcn_update_dpp(0, __float_as_int(x), 0x138, 0xf, 0xf, true));
}
__device__ __forceinline__ float dpp_shl1(float x) {
  return __int_as_float(
      __builtin_amdgcn_update_dpp(0, __float_as_int(x), 0x130, 0xf, 0xf, true));
}

// Register-resident trapezoidal stencil.
// 256 blocks = 64 images x 4 col-slabs (64-col buffer = 32 interior +
// 16-col halo each side). 256 threads = 4 waves x 16 cols. Lane z owns
// rows 2z,2z+1 x 16 cols in registers; a wave spans all 128 rows, so all
// vertical taps come from lane+-1 via DPP (zero LDS). Horizontal taps are
// in-register except the 2-col group edges, exchanged via a tiny
// double-buffered LDS halo (8 ds_b64 per thread per iteration).
__global__ __launch_bounds__(256)
void fd_reg_kernel(const float* __restrict__ x_in, const float* __restrict__ bands,
                   const int* __restrict__ fdp, float* __restrict__ x_out) {
  __shared__ float hbuf[2][4][2][XL][2];   // [buf][wave][side L/R][row][2 cols] = 16 KB

  const int tid = threadIdx.x;
  const int z = tid & 63;        // lane -> row pair
  const int w = tid >> 6;        // wave -> 16-col group
  const int n = blockIdx.x >> 2;
  const int s = blockIdx.x & 3;
  int cs0 = 32 * s - 16; if (cs0 < 0) cs0 = 0; if (cs0 > 64) cs0 = 64;
  const int c0 = cs0 + 16 * w;   // first col owned by this thread
  const int r0 = 2 * z, r1 = 2 * z + 1;

  const float* img = x_in + n * XL * XL;

  // field registers: f0 = row r0, f1 = row r1, 16 cols each
  float f0[16], f1[16];
  {
    const float4* a = (const float4*)(img + r0 * XL + c0);
    const float4* b = (const float4*)(img + r1 * XL + c0);
#pragma unroll
    for (int m = 0; m < 4; ++m) {
      const float4 v = a[m];
      f0[4 * m] = v.x; f0[4 * m + 1] = v.y; f0[4 * m + 2] = v.z; f0[4 * m + 3] = v.w;
      const float4 u = b[m];
      f1[4 * m] = u.x; f1[4 * m + 1] = u.y; f1[4 * m + 2] = u.z; f1[4 * m + 3] = u.w;
    }
  }

  // coefficients. Cols k=2..13 are always interior (image cols 0,1,126,127
  // can only be k=0,1,14,15); rows vary only at z=0,63 -> per-lane load.
  float rbi[5], rbe0[5], rbe1[5], rbe14[5], rbe15[5], cb0[5], cb1[5];
#pragma unroll
  for (int d = 0; d < 5; ++d) {
    rbi[d]   = bands[d * XL + 64];
    rbe0[d]  = bands[d * XL + c0];
    rbe1[d]  = bands[d * XL + c0 + 1];
    rbe14[d] = bands[d * XL + c0 + 14];
    rbe15[d] = bands[d * XL + c0 + 15];
    cb0[d]   = bands[(5 + d) * XL + r0];
    cb1[d]   = bands[(5 + d) * XL + r1];
  }

  const int fdb = fdp[0];
  const int wl = (w > 0) ? w - 1 : 0;   // clamped: garbage-but-finite at slab edge,
  const int wr = (w < 3) ? w + 1 : 3;   // corruption stays inside the 16-col margin

  for (int t = 0; t < fdb; ++t) {
    const int b = t & 1;
    // publish group-edge column pairs
    *(float2*)&hbuf[b][w][0][r0][0] = make_float2(f0[0], f0[1]);
    *(float2*)&hbuf[b][w][0][r1][0] = make_float2(f1[0], f1[1]);
    *(float2*)&hbuf[b][w][1][r0][0] = make_float2(f0[14], f0[15]);
    *(float2*)&hbuf[b][w][1][r1][0] = make_float2(f1[14], f1[15]);
    __syncthreads();
    const float2 lh0 = *(const float2*)&hbuf[b][wl][1][r0][0];  // cols c0-2,c0-1
    const float2 lh1 = *(const float2*)&hbuf[b][wl][1][r1][0];
    const float2 rh0 = *(const float2*)&hbuf[b][wr][0][r0][0];  // cols c0+16,c0+17
    const float2 rh1 = *(const float2*)&hbuf[b][wr][0][r1][0];

    float om2_0 = 0.f, om1_0 = 0.f, om2_1 = 0.f, om1_1 = 0.f;  // old f[k-2], f[k-1]
#pragma unroll
    for (int k = 0; k < 16; ++k) {
      const float o0 = f0[k], o1 = f1[k];
      // vertical taps via DPP: rows r0-2, r0-1 (=r1-2), r1+1, r1+2
      const float vm2 = dpp_shr1(o0);   // lane z-1 row0 = row 2z-2
      const float vm1 = dpp_shr1(o1);   // lane z-1 row1 = row 2z-1
      const float vp2 = dpp_shl1(o0);   // lane z+1 row0 = row 2z+2
      const float vp3 = dpp_shl1(o1);   // lane z+1 row1 = row 2z+3
      // horizontal taps (old values)
      const float hm2_0 = (k == 0) ? lh0.x : (k == 1) ? lh0.y : om2_0;
      const float hm1_0 = (k == 0) ? lh0.y : om1_0;
      const float hm2_1 = (k == 0) ? lh1.x : (k == 1) ? lh1.y : om2_1;
      const float hm1_1 = (k == 0) ? lh1.y : om1_1;
      const float hp1_0 = (k < 15) ? f0[k + 1] : rh0.x;
      const float hp2_0 = (k < 14) ? f0[k + 2] : ((k == 14) ? rh0.x : rh0.y);
      const float hp1_1 = (k < 15) ? f1[k + 1] : rh1.x;
      const float hp2_1 = (k < 14) ? f1[k + 2] : ((k == 14) ? rh1.x : rh1.y);
      // row-band coeffs for this col (compile-time select under unroll)
      float c0b, c1b, c2b, c3b, c4b;
      if (k == 0)       { c0b = rbe0[0];  c1b = rbe0[1];  c2b = rbe0[2];  c3b = rbe0[3];  c4b = rbe0[4];  }
      else if (k == 1)  { c0b = rbe1[0];  c1b = rbe1[1];  c2b = rbe1[2];  c3b = rbe1[3];  c4b = rbe1[4];  }
      else if (k == 14) { c0b = rbe14[0]; c1b = rbe14[1]; c2b = rbe14[2]; c3b = rbe14[3]; c4b = rbe14[4]; }
      else if (k == 15) { c0b = rbe15[0]; c1b = rbe15[1]; c2b = rbe15[2]; c3b = rbe15[3]; c4b = rbe15[4]; }
      else              { c0b = rbi[0];   c1b = rbi[1];   c2b = rbi[2];   c3b = rbi[3];   c4b = rbi[4];   }

      const float n0 = o0
        + c0b * hm2_0 + c1b * hm1_0 + c2b * o0 + c3b * hp1_0 + c4b * hp2_0
        + cb0[0] * vm2 + cb0[1] * vm1 + cb0[2] * o0 + cb0[3] * o1 + cb0[4] * vp2;
      const float n1 = o1
        + c0b * hm2_1 + c1b * hm1_1 + c2b * o1 + c3b * hp1_1 + c4b * hp2_1
        + cb1[0] * vm1 + cb1[1] * o0 + cb1[2] * o1 + cb1[3] * vp2 + cb1[4] * vp3;

      om2_0 = om1_0; om1_0 = o0; om2_1 = om1_1; om1_1 = o1;
      f0[k] = n0; f1[k] = n1;
    }
  }

  // store: only waves whose 16 cols lie in the interior window [32s, 32s+32)
  if (c0 == 32 * s || c0 == 32 * s + 16) {
    float* outp = x_out + n * XL * XL;
    float4* o0p = (float4*)(outp + r0 * XL + c0);
    float4* o1p = (float4*)(outp + r1 * XL + c0);
#pragma unroll
    for (int m = 0; m < 4; ++m) {
      o0p[m] = make_float4(f0[4 * m], f0[4 * m + 1], f0[4 * m + 2], f0[4 * m + 3]);
      o1p[m] = make_float4(f1[4 * m], f1[4 * m + 1], f1[4 * m + 2], f1[4 * m + 3]);
    }
  }
}

extern "C" void kernel_launch(void* const* d_in, const int* in_sizes, int n_in,
                              void* d_out, int out_size, void* d_ws, size_t ws_size,
                              hipStream_t stream) {
  const float* xInput = (const float*)d_in[0];
  const float* wX1  = (const float*)d_in[1];
  const float* wX1L = (const float*)d_in[2];
  const float* wX1R = (const float*)d_in[3];
  const float* wY1  = (const float*)d_in[4];
  const float* wY1L = (const float*)d_in[5];
  const float* wY1R = (const float*)d_in[6];
  const float* wX2  = (const float*)d_in[7];
  const float* wX2L = (const float*)d_in[8];
  const float* wX2R = (const float*)d_in[9];
  const float* wY2  = (const float*)d_in[10];
  const float* wY2L = (const float*)d_in[11];
  const float* wY2R = (const float*)d_in[12];
  const float* wfc  = (const float*)d_in[13];
  const int*   fdp  = (const int*)d_in[14];

  float* bands = (float*)d_ws;   // 2*5*128 floats = 5120 B
  float* out = (float*)d_out;

  build_bands_kernel<<<5, 256, 0, stream>>>(wX1, wX1L, wX1R, wY1, wY1L, wY1R,
                                            wX2, wX2L, wX2R, wY2, wY2L, wY2R,
                                            wfc, bands);
  fd_reg_kernel<<<256, 256, 0, stream>>>(xInput, bands, fdp, out);
}